// Round 3
// baseline (252.550 us; speedup 1.0000x reference)
//
#include <hip/hip_runtime.h>

// TTTConv: depthwise causal conv1d, B=4, N=4096, D=2048, K=4, fp32.
// out[b,n,d] = bias[d] + sum_{k=0..3} w[d,k] * x[b, n-3+k, d]  (x[t<0]=0)
// states[b,d,k] = x[b, N-4+k, d]  -- fused into last-chunk blocks.
//
// R2 -> R3: contiguous-sweep blocks. Each block owns Tb=8 whole rows
// (64 KB contiguous + 24 KB halo), sliding 3-row window in registers,
// so every block streams sequentially (R2's half-row 8KB-stride hops ran
// at 2.5 TB/s). XCD swizzle keeps each XCD on one contiguous 1/8 span.
// Regular stores (nontemporal regressed in R2).

constexpr int B = 4, N = 4096, D = 2048, K = 4;
constexpr int Tb = 8;             // rows per block
constexpr int NB = N / Tb;        // 512 chunks per batch
constexpr int BLK = 256;
constexpr int GRID = B * NB;      // 2048 blocks

__global__ __launch_bounds__(BLK) void tttconv_stream(
    const float* __restrict__ x, const float* __restrict__ w,
    const float* __restrict__ bias, float* __restrict__ out,
    float* __restrict__ st)
{
    // XCD-contiguity swizzle: hw block h -> logical block so XCD k sweeps
    // the contiguous logical range [k*GRID/8, (k+1)*GRID/8).
    int lb = (blockIdx.x & 7) * (GRID / 8) + (blockIdx.x >> 3);
    int b  = lb / NB;
    int nc = lb % NB;
    int n0 = nc * Tb;
    int tid = threadIdx.x;
    int d0 = tid * 4;        // covers d in [0, 1024)
    int d1 = d0 + 1024;      // covers d in [1024, 2048)

    // w is (D,K) row-major: w4[d] = w[d][0..3]
    const float4* w4 = (const float4*)w;
    float4 wa0 = w4[d0], wa1 = w4[d0 + 1], wa2 = w4[d0 + 2], wa3 = w4[d0 + 3];
    float4 wb0 = w4[d1], wb1 = w4[d1 + 1], wb2 = w4[d1 + 2], wb3 = w4[d1 + 3];
    float4 bva = *(const float4*)(bias + d0);
    float4 bvb = *(const float4*)(bias + d1);

    const float* xb = x + ((size_t)b * N) * D;
    float* ob = out + ((size_t)b * N) * D;

    // sliding window: rows n-3, n-2, n-1 (a: low half, bw: high half)
    float4 a0, a1, a2, c0, c1, c2;
    if (nc > 0) {
        a0 = *(const float4*)(xb + (size_t)(n0 - 3) * D + d0);
        c0 = *(const float4*)(xb + (size_t)(n0 - 3) * D + d1);
        a1 = *(const float4*)(xb + (size_t)(n0 - 2) * D + d0);
        c1 = *(const float4*)(xb + (size_t)(n0 - 2) * D + d1);
        a2 = *(const float4*)(xb + (size_t)(n0 - 1) * D + d0);
        c2 = *(const float4*)(xb + (size_t)(n0 - 1) * D + d1);
    } else {
        a0 = a1 = a2 = make_float4(0.f, 0.f, 0.f, 0.f);
        c0 = c1 = c2 = a0;
    }

    #pragma unroll
    for (int t = 0; t < Tb; ++t) {
        size_t roff = (size_t)(n0 + t) * D;
        float4 ca = *(const float4*)(xb + roff + d0);
        float4 cb = *(const float4*)(xb + roff + d1);

        float4 oa, oc;
        oa.x = bva.x + wa0.x * a0.x + wa0.y * a1.x + wa0.z * a2.x + wa0.w * ca.x;
        oa.y = bva.y + wa1.x * a0.y + wa1.y * a1.y + wa1.z * a2.y + wa1.w * ca.y;
        oa.z = bva.z + wa2.x * a0.z + wa2.y * a1.z + wa2.z * a2.z + wa2.w * ca.z;
        oa.w = bva.w + wa3.x * a0.w + wa3.y * a1.w + wa3.z * a2.w + wa3.w * ca.w;
        oc.x = bvb.x + wb0.x * c0.x + wb0.y * c1.x + wb0.z * c2.x + wb0.w * cb.x;
        oc.y = bvb.y + wb1.x * c0.y + wb1.y * c1.y + wb1.z * c2.y + wb1.w * cb.y;
        oc.z = bvb.z + wb2.x * c0.z + wb2.y * c1.z + wb2.z * c2.z + wb2.w * cb.z;
        oc.w = bvb.w + wb3.x * c0.w + wb3.y * c1.w + wb3.z * c2.w + wb3.w * cb.w;

        *(float4*)(ob + roff + d0) = oa;
        *(float4*)(ob + roff + d1) = oc;

        // conv_states from live window: rows N-4..N-1 = a0,a1,a2,ca
        if (t == Tb - 1 && nc == NB - 1) {
            float4* sa = (float4*)(st + ((size_t)b * D + d0) * K);
            sa[0] = make_float4(a0.x, a1.x, a2.x, ca.x);
            sa[1] = make_float4(a0.y, a1.y, a2.y, ca.y);
            sa[2] = make_float4(a0.z, a1.z, a2.z, ca.z);
            sa[3] = make_float4(a0.w, a1.w, a2.w, ca.w);
            float4* sb = (float4*)(st + ((size_t)b * D + d1) * K);
            sb[0] = make_float4(c0.x, c1.x, c2.x, cb.x);
            sb[1] = make_float4(c0.y, c1.y, c2.y, cb.y);
            sb[2] = make_float4(c0.z, c1.z, c2.z, cb.z);
            sb[3] = make_float4(c0.w, c1.w, c2.w, cb.w);
        }

        a0 = a1; a1 = a2; a2 = ca;
        c0 = c1; c1 = c2; c2 = cb;
    }
}

extern "C" void kernel_launch(void* const* d_in, const int* in_sizes, int n_in,
                              void* d_out, int out_size, void* d_ws, size_t ws_size,
                              hipStream_t stream)
{
    const float* x    = (const float*)d_in[0];
    const float* w    = (const float*)d_in[1];
    const float* bias = (const float*)d_in[2];
    float* out = (float*)d_out;
    float* st  = out + (size_t)B * N * D;

    tttconv_stream<<<GRID, BLK, 0, stream>>>(x, w, bias, out, st);
}

// Round 4
// 238.762 us; speedup vs baseline: 1.0577x; 1.0577x over previous
//
#include <hip/hip_runtime.h>

// TTTConv: depthwise causal conv1d, B=4, N=4096, D=2048, K=4, fp32.
// out[b,n,d] = bias[d] + sum_{k=0..3} w[d,k] * x[b, n-3+k, d]  (x[t<0]=0)
// states[b,d,k] = x[b, N-4+k, d]  -- fused into last-chunk blocks.
//
// R3 -> R4: the ~2.4 TB/s plateau was register-budget load serialization:
// default launch_bounds capped VGPRs at 56/40, so the 19-row load batch
// couldn't live in registers and the compiler emitted serial load->use
// round-trips. __launch_bounds__(256,1) unlocks ~512 VGPR/wave so all
// T+3=19 float4 loads stay in flight. Natural block order (dblk fastest)
// restored -- R3's XCD swizzle hurt L3 hit rate. Regular stores.

constexpr int B = 4, N = 4096, D = 2048, K = 4;
constexpr int T = 16;             // timesteps per thread
constexpr int BLK = 256;          // threads per block
constexpr int DBLKS = 2;          // 2 d-blocks cover D/4=512 float4 lanes
constexpr int NCHUNKS = N / T;    // 256 n-chunks
constexpr int GRID = B * NCHUNKS * DBLKS;  // 2048 blocks

__global__ __launch_bounds__(BLK, 1) void tttconv_batch(
    const float* __restrict__ x, const float* __restrict__ w,
    const float* __restrict__ bias, float* __restrict__ out,
    float* __restrict__ st)
{
    int bid = blockIdx.x;
    int dblk = bid & (DBLKS - 1);
    int nchunk = (bid / DBLKS) % NCHUNKS;
    int b = bid / (DBLKS * NCHUNKS);
    int dv = dblk * BLK + threadIdx.x;   // 0..511
    int d = dv * 4;
    int n0 = nchunk * T;

    const float* xbase = x + ((size_t)b * N) * D + d;

    // ---- batched x loads: all T+3 rows in flight before any use ----
    float4 xin[T + K - 1];
    if (nchunk > 0) {
        #pragma unroll
        for (int j = 0; j < T + K - 1; ++j)
            xin[j] = *(const float4*)(xbase + (size_t)(n0 - (K - 1) + j) * D);
    } else {
        #pragma unroll
        for (int j = 0; j < T + K - 1; ++j) {
            int n = n0 - (K - 1) + j;
            xin[j] = (n >= 0) ? *(const float4*)(xbase + (size_t)n * D)
                              : make_float4(0.f, 0.f, 0.f, 0.f);
        }
    }

    // ---- weights & bias (L2-warm, issued after the HBM-critical loads) ----
    const float4* w4 = (const float4*)(w + (size_t)d * K);
    float4 wr0 = w4[0];
    float4 wr1 = w4[1];
    float4 wr2 = w4[2];
    float4 wr3 = w4[3];
    float4 bv = *(const float4*)(bias + d);

    float* obase = out + ((size_t)b * N) * D + d;
    #pragma unroll
    for (int t = 0; t < T; ++t) {
        float4 acc = bv;
        // channel c uses wr_c; input row n0+t-3+k -> xin[t+k]
        acc.x += wr0.x * xin[t + 0].x + wr0.y * xin[t + 1].x + wr0.z * xin[t + 2].x + wr0.w * xin[t + 3].x;
        acc.y += wr1.x * xin[t + 0].y + wr1.y * xin[t + 1].y + wr1.z * xin[t + 2].y + wr1.w * xin[t + 3].y;
        acc.z += wr2.x * xin[t + 0].z + wr2.y * xin[t + 1].z + wr2.z * xin[t + 2].z + wr2.w * xin[t + 3].z;
        acc.w += wr3.x * xin[t + 0].w + wr3.y * xin[t + 1].w + wr3.z * xin[t + 2].w + wr3.w * xin[t + 3].w;
        *(float4*)(obase + (size_t)(n0 + t) * D) = acc;
    }

    // conv_states: rows N-4..N-1 = xin[T-1 .. T+2] in the last n-chunk
    if (nchunk == NCHUNKS - 1) {
        float4* stp = (float4*)(st + ((size_t)b * D + d) * K);
        stp[0] = make_float4(xin[T - 1].x, xin[T].x, xin[T + 1].x, xin[T + 2].x);
        stp[1] = make_float4(xin[T - 1].y, xin[T].y, xin[T + 1].y, xin[T + 2].y);
        stp[2] = make_float4(xin[T - 1].z, xin[T].z, xin[T + 1].z, xin[T + 2].z);
        stp[3] = make_float4(xin[T - 1].w, xin[T].w, xin[T + 1].w, xin[T + 2].w);
    }
}

extern "C" void kernel_launch(void* const* d_in, const int* in_sizes, int n_in,
                              void* d_out, int out_size, void* d_ws, size_t ws_size,
                              hipStream_t stream)
{
    const float* x    = (const float*)d_in[0];
    const float* w    = (const float*)d_in[1];
    const float* bias = (const float*)d_in[2];
    float* out = (float*)d_out;
    float* st  = out + (size_t)B * N * D;

    tttconv_batch<<<GRID, BLK, 0, stream>>>(x, w, bias, out, st);
}